// Round 1
// baseline (188.432 us; speedup 1.0000x reference)
//
#include <hip/hip_runtime.h>
#include <math.h>

// Problem constants (from reference): B=32, C=2, L=262144, K=4
#define B_N 32
#define C_N 2
#define L_N 262144
#define K_N 4
#define NSEQ (B_N * C_N)          // 64 independent sequences
#define CHUNK 256                 // samples per chunk-thread
#define NCHUNK (L_N / CHUNK)      // 1024 chunks per sequence
#define NLVL 10                   // log2(NCHUNK) scan levels
// d_ws float layout: [coef: 32*4*5 = 640][mats: 32*10*64 = 20480]  (~84.5 KB)
#define WS_COEF 0
#define WS_MATS (B_N * K_N * 5)

// ---------------------------------------------------------------------------
// K1: per-batch coefficient prep + transition-matrix powers (fp64).
// 32 blocks (one per b) x 64 threads. Lane (i,j) owns element [i][j] of the
// 8x8 cascade transition matrix during repeated squaring.
// ---------------------------------------------------------------------------
__global__ __launch_bounds__(64) void svf_prep(
    const float* __restrict__ twoR, const float* __restrict__ Graw,
    const float* __restrict__ c_hp, const float* __restrict__ c_bp,
    const float* __restrict__ c_lp, float* __restrict__ ws)
{
    const int b = blockIdx.x;
    const int t = threadIdx.x;
    __shared__ double cf[K_N][5];   // b0,b1,b2,a1,a2 (normalized, a0==1)
    __shared__ double M[8][8];

    if (t < K_N) {
        const int k = t;
        double g  = (double)Graw[b * K_N + k];
        double tr = (double)twoR[b * K_N + k];
        double hp = (double)c_hp[b * K_N + k];
        double bp = (double)c_bp[b * K_N + k];
        double lp = (double)c_lp[b * K_N + k];
        double sg = 1.0 / (1.0 + exp(-g));
        double G  = tan(1.5707963267948966 * sg);
        double R  = log1p(exp(tr)) * 1.4426950408889634 + 0.01; // softplus/ln2 + .01
        double G2 = G * G;
        double b0 = hp + bp * G + lp * G2;
        double b1 = -2.0 * hp + 2.0 * lp * G2;
        double b2 = hp - bp * G + lp * G2;
        double a0 = 1.0 + G2 + R * G;
        double a1 = 2.0 * G2 - 2.0;
        double a2 = 1.0 + G2 - R * G;
        cf[k][0] = b0 / a0; cf[k][1] = b1 / a0; cf[k][2] = b2 / a0;
        cf[k][3] = a1 / a0; cf[k][4] = a2 / a0;
    }
    __syncthreads();

    if (t < 20) ws[WS_COEF + b * 20 + t] = (float)cf[t / 5][t % 5];

    // Build A columns: one cascade step from s = e_t, x = 0.
    if (t < 8) {
        double s[8];
        #pragma unroll
        for (int i = 0; i < 8; ++i) s[i] = (i == t) ? 1.0 : 0.0;
        double in = 0.0;
        #pragma unroll
        for (int k = 0; k < K_N; ++k) {
            double y   = cf[k][0] * in + s[2 * k];
            double s1n = cf[k][1] * in - cf[k][3] * y + s[2 * k + 1];
            double s2n = cf[k][2] * in - cf[k][4] * y;
            s[2 * k] = s1n; s[2 * k + 1] = s2n; in = y;
        }
        #pragma unroll
        for (int i = 0; i < 8; ++i) M[i][t] = s[i];
    }
    __syncthreads();

    // Repeated squaring: after p squarings M = A^(2^p).
    // Store fp32 copies of A^(2^8) .. A^(2^17)  (= (A^CHUNK)^(2^l), l=0..9).
    const int i = t >> 3, j = t & 7;
    for (int p = 1; p <= 17; ++p) {
        double acc = 0.0;
        #pragma unroll
        for (int k = 0; k < 8; ++k) acc += M[i][k] * M[k][j];
        __syncthreads();          // everyone finished reading old M
        M[i][j] = acc;
        __syncthreads();          // writes visible before next round's reads
        if (p >= 8) ws[WS_MATS + (b * NLVL + (p - 8)) * 64 + t] = (float)acc;
    }
}

// ---------------------------------------------------------------------------
// Fused 4-biquad cascade step (normalized coefficients).
// 5 VALU ops per filter, 20 per sample.
// ---------------------------------------------------------------------------
__device__ __forceinline__ float cascade_step(const float cf[20], float s[8], float in)
{
    #pragma unroll
    for (int k = 0; k < K_N; ++k) {
        float y  = fmaf(cf[k * 5 + 0], in, s[2 * k]);
        float t1 = fmaf(cf[k * 5 + 1], in, s[2 * k + 1]);
        float n1 = fmaf(-cf[k * 5 + 3], y, t1);
        float n2 = fmaf(-cf[k * 5 + 4], y, cf[k * 5 + 2] * in);
        s[2 * k] = n1; s[2 * k + 1] = n2;
        in = y;
    }
    return in;
}

// ---------------------------------------------------------------------------
// K2: zero-state pass. One thread per 256-sample chunk; writes final 8-state
// f into this thread's OWN slice of d_out (offset +8 floats) — race-free.
// ---------------------------------------------------------------------------
__global__ __launch_bounds__(256) void svf_pass1(
    const float* __restrict__ x, const float* __restrict__ ws,
    float* __restrict__ out)
{
    const int g   = blockIdx.x * blockDim.x + threadIdx.x;
    const int seq = g >> 10;              // g / NCHUNK
    const int ci  = g & (NCHUNK - 1);
    const int b   = seq >> 1;             // seq / C
    float cf[20];
    #pragma unroll
    for (int q = 0; q < 20; ++q) cf[q] = ws[WS_COEF + b * 20 + q];

    const size_t base = (size_t)seq * L_N + (size_t)ci * CHUNK;
    const float4* xp = (const float4*)(x + base);
    float s[8] = {0, 0, 0, 0, 0, 0, 0, 0};

    for (int t4 = 0; t4 < CHUNK / 4; ++t4) {
        float4 v = xp[t4];
        (void)cascade_step(cf, s, v.x);
        (void)cascade_step(cf, s, v.y);
        (void)cascade_step(cf, s, v.z);
        (void)cascade_step(cf, s, v.w);
    }
    float4* fo = (float4*)(out + base + 8);
    fo[0] = make_float4(s[0], s[1], s[2], s[3]);
    fo[1] = make_float4(s[4], s[5], s[6], s[7]);
}

// ---------------------------------------------------------------------------
// K3: per-sequence Kogge-Stone scan over the 1024 chunk maps.
// t_i <- t_i + P^(2^l) * t_{i-2^l}; afterwards chunk i's initial state is
// S_i = t_{i-1}. One block (1024 threads) per sequence.
// ---------------------------------------------------------------------------
__global__ __launch_bounds__(1024) void svf_scan(
    const float* __restrict__ ws, float* __restrict__ out)
{
    const int seq = blockIdx.x;
    const int i   = threadIdx.x;
    const int b   = seq >> 1;
    __shared__ float Pm[NLVL][64];
    __shared__ float tb[NCHUNK][9];       // pad 8->9 to break bank conflicts

    for (int q = threadIdx.x; q < NLVL * 64; q += blockDim.x)
        Pm[q >> 6][q & 63] = ws[WS_MATS + b * NLVL * 64 + q];

    const size_t base = (size_t)seq * L_N + (size_t)i * CHUNK;
    const float4* fp = (const float4*)(out + base + 8);
    float4 f0 = fp[0], f1 = fp[1];
    float t[8] = {f0.x, f0.y, f0.z, f0.w, f1.x, f1.y, f1.z, f1.w};
    __syncthreads();    // Pm loaded

    for (int l = 0; l < NLVL; ++l) {
        const int d = 1 << l;
        #pragma unroll
        for (int q = 0; q < 8; ++q) tb[i][q] = t[q];
        __syncthreads();
        float prev[8];
        const bool have = (i >= d);
        if (have) {
            #pragma unroll
            for (int q = 0; q < 8; ++q) prev[q] = tb[i - d][q];
        }
        __syncthreads();
        if (have) {
            #pragma unroll
            for (int r = 0; r < 8; ++r) {
                float acc = t[r];
                #pragma unroll
                for (int c = 0; c < 8; ++c)
                    acc = fmaf(Pm[l][r * 8 + c], prev[c], acc);
                t[r] = acc;
            }
        }
    }

    // publish inclusive results once more; S_i = t_{i-1} (S_0 = 0)
    #pragma unroll
    for (int q = 0; q < 8; ++q) tb[i][q] = t[q];
    __syncthreads();
    float* so = out + base;
    if (i == 0) {
        #pragma unroll
        for (int q = 0; q < 8; ++q) so[q] = 0.0f;
    } else {
        #pragma unroll
        for (int q = 0; q < 8; ++q) so[q] = tb[i - 1][q];
    }
}

// ---------------------------------------------------------------------------
// K4: final pass. Read own chunk's initial state (written by K3 into this
// thread's own output slice), rerun the cascade, write y.
// ---------------------------------------------------------------------------
__global__ __launch_bounds__(256) void svf_pass2(
    const float* __restrict__ x, const float* __restrict__ ws,
    float* __restrict__ out)
{
    const int g   = blockIdx.x * blockDim.x + threadIdx.x;
    const int seq = g >> 10;
    const int ci  = g & (NCHUNK - 1);
    const int b   = seq >> 1;
    float cf[20];
    #pragma unroll
    for (int q = 0; q < 20; ++q) cf[q] = ws[WS_COEF + b * 20 + q];

    const size_t base = (size_t)seq * L_N + (size_t)ci * CHUNK;
    const float4* sp = (const float4*)(out + base);
    float4 s0 = sp[0], s1v = sp[1];
    float s[8] = {s0.x, s0.y, s0.z, s0.w, s1v.x, s1v.y, s1v.z, s1v.w};

    const float4* xp = (const float4*)(x + base);
    float4* yp = (float4*)(out + base);
    for (int t4 = 0; t4 < CHUNK / 4; ++t4) {
        float4 v = xp[t4];
        float y0 = cascade_step(cf, s, v.x);
        float y1 = cascade_step(cf, s, v.y);
        float y2 = cascade_step(cf, s, v.z);
        float y3 = cascade_step(cf, s, v.w);
        yp[t4] = make_float4(y0, y1, y2, y3);
    }
}

// ---------------------------------------------------------------------------
extern "C" void kernel_launch(void* const* d_in, const int* in_sizes, int n_in,
                              void* d_out, int out_size, void* d_ws, size_t ws_size,
                              hipStream_t stream)
{
    (void)in_sizes; (void)n_in; (void)out_size; (void)ws_size;
    const float* x    = (const float*)d_in[0];
    const float* twoR = (const float*)d_in[1];
    const float* G    = (const float*)d_in[2];
    const float* chp  = (const float*)d_in[3];
    const float* cbp  = (const float*)d_in[4];
    const float* clp  = (const float*)d_in[5];
    float* out = (float*)d_out;
    float* ws  = (float*)d_ws;

    svf_prep <<<B_N, 64, 0, stream>>>(twoR, G, chp, cbp, clp, ws);
    svf_pass1<<<NSEQ * NCHUNK / 256, 256, 0, stream>>>(x, ws, out);
    svf_scan <<<NSEQ, NCHUNK, 0, stream>>>(ws, out);
    svf_pass2<<<NSEQ * NCHUNK / 256, 256, 0, stream>>>(x, ws, out);
}